// Round 10
// baseline (84.870 us; speedup 1.0000x reference)
//
#include <hip/hip_runtime.h>

// Problem dims (fixed by setup_inputs): feat [B,H,W,D,F] float32
#define BB 32
#define HH 128
#define WW 128
#define DD 16
#define FF 8
#define VEC_PER_ROW 32              // DD*FF floats = 32 float4 per (b,h,w) row
#define HW (HH * WW)
#define PLANE_VEC (HW * VEC_PER_ROW)      // 524288 float4 per batch plane (2^19)

// Structure = R8 (best, 81.6us): h-fast traversal, NT stores, zero-skip,
// oversubscribed grid. R10 change: MLP depth 4 -> 8 (8 planes per thread,
// all 8 loads in flight before the first store). Threads = 2^21, grid 8192
// = 4x resident capacity (still ample dynamic balancing; invalid ~4%).
#define BLK  256
#define GRID (4 * PLANE_VEC / BLK)        // 8192

typedef float f32x4 __attribute__((ext_vector_type(4)));

// ---------------------------------------------------------------------------
// Kernel 1: build the (h,w)->source-row map. One entry per output (h,w):
//   map[h*W+w] = yi*W + xi  (source plane row index) or -1 if rotation-invalid.
// Composition (output -> input): flip2 -> roll -> rotate.
// Float math replicates the reference EXACTLY: double trig cast to f32,
// pure f32 mul/add (no FMA contraction), rintf = round-half-even (np.round).
// ---------------------------------------------------------------------------
__global__ void build_map_kernel(const int* __restrict__ rot_deg,
                                 const int* __restrict__ shift_h,
                                 const int* __restrict__ shift_w,
                                 const int* __restrict__ flip2,
                                 int* __restrict__ map) {
    int idx = blockIdx.x * blockDim.x + threadIdx.x;
    if (idx >= HW) return;
    int h = idx >> 7;
    int w = idx & (WW - 1);

    int sh = *shift_h;
    int sw = *shift_w;
    int f2 = *flip2;

    double th = (double)(*rot_deg) * (3.14159265358979323846 / 180.0);
    float c = (float)cos(th);
    float s = (float)sin(th);
    const float xc = (float)(WW - 1) * 0.5f;
    const float yc = (float)(HH - 1) * 0.5f;

    int i  = (h - sh) & (HH - 1);              // inverse roll (rows)
    int w1 = f2 ? (WW - 1 - w) : w;            // inverse flip (cols)
    int j  = (w1 - sw) & (WW - 1);             // inverse roll (cols)

    float dx = (float)j - xc;
    float dy = (float)i - yc;
    float xs = __fadd_rn(__fadd_rn(__fmul_rn(c, dx), __fmul_rn(s, dy)), xc);
    float ys = __fadd_rn(__fadd_rn(__fmul_rn(-s, dx), __fmul_rn(c, dy)), yc);
    int xi = (int)rintf(xs);
    int yi = (int)rintf(ys);
    bool valid = (xi >= 0) && (xi < WW) && (yi >= 0) && (yi < HH);
    map[idx] = valid ? (yi * WW + xi) : -1;
}

// ---------------------------------------------------------------------------
// Kernel 2: row gather, h-FAST traversal + NT stores + 8-deep MLP.
//   t in [0, 4*PLANE_VEC):
//     k  = t & 31          float4 slot within the 512B row
//     h  = (t >> 5) & 127  FAST spatial dim -> near-sequential source reads
//     w  = (t >> 12) & 127
//     b0 = t >> 19         in [0,4); planes b0 + 4u, u = 0..7
// All 8 loads issued back-to-back (8 outstanding per thread), then 8 NT
// stores. Invalid rows: zero-store only, reads skipped.
// ---------------------------------------------------------------------------
__global__ void __launch_bounds__(BLK)
gather_kernel(const f32x4* __restrict__ src,
              f32x4* __restrict__ dst,
              const int* __restrict__ map,
              const int* __restrict__ flip3) {
    const int t  = blockIdx.x * BLK + (int)threadIdx.x;   // [0, 4*PLANE_VEC)
    const int k  = t & (VEC_PER_ROW - 1);
    const int h  = (t >> 5) & (HH - 1);
    const int w  = (t >> 12) & (WW - 1);
    const int b0 = t >> 19;                               // [0, 4)
    const int hw = (h << 7) | w;
    const int m  = map[hw];

    const size_t slot = ((size_t)hw << 5) + (size_t)k;    // float4 idx in plane
    f32x4* __restrict__ d = dst + ((size_t)b0 << 19) + slot;

    if (m >= 0) {
        const int f3 = *flip3;
        // flip3 reverses D (16 slots of 2 float4) within the row
        const int kk = f3 ? ((((DD - 1) - (k >> 1)) << 1) | (k & 1)) : k;
        const f32x4* __restrict__ s =
            src + ((size_t)b0 << 19) + ((size_t)m << 5) + (size_t)kk;
        f32x4 v[8];
        #pragma unroll
        for (int u = 0; u < 8; ++u)
            v[u] = s[(size_t)(4 * u) * PLANE_VEC];        // plain loads (cache)
        #pragma unroll
        for (int u = 0; u < 8; ++u)
            __builtin_nontemporal_store(v[u], d + (size_t)(4 * u) * PLANE_VEC);
    } else {
        const f32x4 z = (f32x4){0.f, 0.f, 0.f, 0.f};
        #pragma unroll
        for (int u = 0; u < 8; ++u)
            __builtin_nontemporal_store(z, d + (size_t)(4 * u) * PLANE_VEC);
    }
}

extern "C" void kernel_launch(void* const* d_in, const int* in_sizes, int n_in,
                              void* d_out, int out_size, void* d_ws, size_t ws_size,
                              hipStream_t stream) {
    const float* feat = (const float*)d_in[0];
    const int* rot    = (const int*)d_in[1];
    const int* sh     = (const int*)d_in[2];
    const int* sw     = (const int*)d_in[3];
    const int* f2     = (const int*)d_in[4];
    const int* f3     = (const int*)d_in[5];
    float* out = (float*)d_out;

    int* map = (int*)d_ws;   // 64 KB; ws proven sufficient
    build_map_kernel<<<(HW + 255) / 256, 256, 0, stream>>>(rot, sh, sw, f2, map);
    gather_kernel<<<GRID, BLK, 0, stream>>>((const f32x4*)feat, (f32x4*)out, map, f3);
}

// Round 11
// 82.257 us; speedup vs baseline: 1.0318x; 1.0318x over previous
//
#include <hip/hip_runtime.h>

// Problem dims (fixed by setup_inputs): feat [B,H,W,D,F] float32
#define BB 32
#define HH 128
#define WW 128
#define DD 16
#define FF 8
#define VEC_PER_ROW 32              // DD*FF floats = 32 float4 per (b,h,w) row
#define HW (HH * WW)
#define PLANE_VEC (HW * VEC_PER_ROW)      // 524288 float4 per batch plane (2^19)

// Structure = R8 (best, 81.6us): h-fast traversal, 4 planes/thread, 8x
// oversubscribed grid, zero-skip. R11 change: stores via inline asm
// `global_store_dwordx4 ..., off sc0 sc1 nt` — full streaming/no-allocate
// policy (L2 *and* MALL). The input is exactly 256 MiB = L3 size; if the
// write stream stops allocating in the Infinity Cache, the input stays
// L3-resident and FETCH_SIZE (119 MB) collapses.
#define BLK  256
#define GRID (8 * PLANE_VEC / BLK)        // 16384

typedef float f32x4 __attribute__((ext_vector_type(4)));

__device__ __forceinline__ void store_stream(f32x4 v, f32x4* p) {
    // no-allocate streaming store at all cache levels
    asm volatile("global_store_dwordx4 %0, %1, off sc0 sc1 nt"
                 :: "v"(p), "v"(v) : "memory");
}

// ---------------------------------------------------------------------------
// Kernel 1: build the (h,w)->source-row map. One entry per output (h,w):
//   map[h*W+w] = yi*W + xi  (source plane row index) or -1 if rotation-invalid.
// Composition (output -> input): flip2 -> roll -> rotate.
// Float math replicates the reference EXACTLY: double trig cast to f32,
// pure f32 mul/add (no FMA contraction), rintf = round-half-even (np.round).
// ---------------------------------------------------------------------------
__global__ void build_map_kernel(const int* __restrict__ rot_deg,
                                 const int* __restrict__ shift_h,
                                 const int* __restrict__ shift_w,
                                 const int* __restrict__ flip2,
                                 int* __restrict__ map) {
    int idx = blockIdx.x * blockDim.x + threadIdx.x;
    if (idx >= HW) return;
    int h = idx >> 7;
    int w = idx & (WW - 1);

    int sh = *shift_h;
    int sw = *shift_w;
    int f2 = *flip2;

    double th = (double)(*rot_deg) * (3.14159265358979323846 / 180.0);
    float c = (float)cos(th);
    float s = (float)sin(th);
    const float xc = (float)(WW - 1) * 0.5f;
    const float yc = (float)(HH - 1) * 0.5f;

    int i  = (h - sh) & (HH - 1);              // inverse roll (rows)
    int w1 = f2 ? (WW - 1 - w) : w;            // inverse flip (cols)
    int j  = (w1 - sw) & (WW - 1);             // inverse roll (cols)

    float dx = (float)j - xc;
    float dy = (float)i - yc;
    float xs = __fadd_rn(__fadd_rn(__fmul_rn(c, dx), __fmul_rn(s, dy)), xc);
    float ys = __fadd_rn(__fadd_rn(__fmul_rn(-s, dx), __fmul_rn(c, dy)), yc);
    int xi = (int)rintf(xs);
    int yi = (int)rintf(ys);
    bool valid = (xi >= 0) && (xi < WW) && (yi >= 0) && (yi < HH);
    map[idx] = valid ? (yi * WW + xi) : -1;
}

// ---------------------------------------------------------------------------
// Kernel 2: row gather, h-FAST traversal + 8x oversubscription + 4-plane MLP
// + streaming stores (sc0 sc1 nt).
//   t in [0, 8*PLANE_VEC):
//     k  = t & 31          float4 slot within the 512B row
//     h  = (t >> 5) & 127  FAST spatial dim  -> near-sequential source reads
//     w  = (t >> 12) & 127
//     b0 = t >> 19         plane group; planes b0 + 8u, u = 0..3
// ---------------------------------------------------------------------------
__global__ void __launch_bounds__(BLK)
gather_kernel(const f32x4* __restrict__ src,
              f32x4* __restrict__ dst,
              const int* __restrict__ map,
              const int* __restrict__ flip3) {
    const int t  = blockIdx.x * BLK + (int)threadIdx.x;   // [0, 8*PLANE_VEC)
    const int k  = t & (VEC_PER_ROW - 1);
    const int h  = (t >> 5) & (HH - 1);
    const int w  = (t >> 12) & (WW - 1);
    const int b0 = t >> 19;                               // [0, 8)
    const int hw = (h << 7) | w;
    const int m  = map[hw];

    const size_t slot = ((size_t)hw << 5) + (size_t)k;    // float4 idx in plane
    f32x4* __restrict__ d = dst + ((size_t)b0 << 19) + slot;

    if (m >= 0) {
        const int f3 = *flip3;
        // flip3 reverses D (16 slots of 2 float4) within the row
        const int kk = f3 ? ((((DD - 1) - (k >> 1)) << 1) | (k & 1)) : k;
        const f32x4* __restrict__ s =
            src + ((size_t)b0 << 19) + ((size_t)m << 5) + (size_t)kk;
        f32x4 v0 = s[(size_t)(8 * 0) * PLANE_VEC];   // loads: PLAIN (cache!)
        f32x4 v1 = s[(size_t)(8 * 1) * PLANE_VEC];
        f32x4 v2 = s[(size_t)(8 * 2) * PLANE_VEC];
        f32x4 v3 = s[(size_t)(8 * 3) * PLANE_VEC];
        store_stream(v0, d + (size_t)(8 * 0) * PLANE_VEC);
        store_stream(v1, d + (size_t)(8 * 1) * PLANE_VEC);
        store_stream(v2, d + (size_t)(8 * 2) * PLANE_VEC);
        store_stream(v3, d + (size_t)(8 * 3) * PLANE_VEC);
    } else {
        const f32x4 z = (f32x4){0.f, 0.f, 0.f, 0.f};
        store_stream(z, d + (size_t)(8 * 0) * PLANE_VEC);
        store_stream(z, d + (size_t)(8 * 1) * PLANE_VEC);
        store_stream(z, d + (size_t)(8 * 2) * PLANE_VEC);
        store_stream(z, d + (size_t)(8 * 3) * PLANE_VEC);
    }
}

extern "C" void kernel_launch(void* const* d_in, const int* in_sizes, int n_in,
                              void* d_out, int out_size, void* d_ws, size_t ws_size,
                              hipStream_t stream) {
    const float* feat = (const float*)d_in[0];
    const int* rot    = (const int*)d_in[1];
    const int* sh     = (const int*)d_in[2];
    const int* sw     = (const int*)d_in[3];
    const int* f2     = (const int*)d_in[4];
    const int* f3     = (const int*)d_in[5];
    float* out = (float*)d_out;

    int* map = (int*)d_ws;   // 64 KB; ws proven sufficient
    build_map_kernel<<<(HW + 255) / 256, 256, 0, stream>>>(rot, sh, sw, f2, map);
    gather_kernel<<<GRID, BLK, 0, stream>>>((const f32x4*)feat, (f32x4*)out, map, f3);
}